// Round 3
// baseline (121.518 us; speedup 1.0000x reference)
//
#include <hip/hip_runtime.h>

#define IMG_W 2048
#define NUM_NODES 255
#define NLEAF 128
#define DEPTH 7
#define XS 68   // padded LDS row stride (floats): bank base 4p, +k span -> 2 lanes/bank = free

// ---------------- K1: tree descent, 4 lanes per patch, nodes from global/L2 --
__global__ __launch_bounds__(256) void descendK(const float* __restrict__ img,
                                                const float* __restrict__ nodes,
                                                float* __restrict__ leaf_out,
                                                float* __restrict__ S,
                                                unsigned* __restrict__ cnt)
{
    const int t = threadIdx.x;
    const int b = blockIdx.x;

    // fold the S/cnt zero-init into this kernel (K1->K2 kernel boundary orders it)
    if (b < 33) {
        const int i = b * 256 + t;
        if (i < NLEAF * 64) S[i] = 0.0f;
        if (i < NLEAF) cnt[i] = 0u;
    }

    const int g = t >> 2;          // patch-group within block
    const int q = t & 3;           // quarter: elements [16q, 16q+16)
    const int p = b * 64 + g;      // patch id 0..65535
    const int r = p >> 8, c = p & 255;

    // my quarter-patch: pixel rows 2q, 2q+1 (8 px each) = 4 float4
    float4 xv0, xv1, xv2, xv3;
    {
        const float* row0 = img + (size_t)(r * 8 + 2 * q) * IMG_W + c * 8;
        xv0 = *(const float4*)(row0);
        xv1 = *(const float4*)(row0 + 4);
        const float* row1 = row0 + IMG_W;
        xv2 = *(const float4*)(row1);
        xv3 = *(const float4*)(row1 + 4);
    }

    int cur = 0;
    #pragma unroll
    for (int lvl = 0; lvl < DEPTH; ++lvl) {
        const int c0 = 2 * cur + 1;
        const float4* n0 = (const float4*)(nodes + c0 * 64 + q * 16);
        const float4* n1 = (const float4*)(nodes + (c0 + 1) * 64 + q * 16);
        const float4 a0 = n0[0], a1 = n0[1], a2 = n0[2], a3 = n0[3];
        const float4 b0 = n1[0], b1 = n1[1], b2 = n1[2], b3 = n1[3];
        float s0 = 0.f, s1 = 0.f;
        float d;
        d = a0.x - xv0.x; s0 = fmaf(d, d, s0);  d = b0.x - xv0.x; s1 = fmaf(d, d, s1);
        d = a0.y - xv0.y; s0 = fmaf(d, d, s0);  d = b0.y - xv0.y; s1 = fmaf(d, d, s1);
        d = a0.z - xv0.z; s0 = fmaf(d, d, s0);  d = b0.z - xv0.z; s1 = fmaf(d, d, s1);
        d = a0.w - xv0.w; s0 = fmaf(d, d, s0);  d = b0.w - xv0.w; s1 = fmaf(d, d, s1);
        d = a1.x - xv1.x; s0 = fmaf(d, d, s0);  d = b1.x - xv1.x; s1 = fmaf(d, d, s1);
        d = a1.y - xv1.y; s0 = fmaf(d, d, s0);  d = b1.y - xv1.y; s1 = fmaf(d, d, s1);
        d = a1.z - xv1.z; s0 = fmaf(d, d, s0);  d = b1.z - xv1.z; s1 = fmaf(d, d, s1);
        d = a1.w - xv1.w; s0 = fmaf(d, d, s0);  d = b1.w - xv1.w; s1 = fmaf(d, d, s1);
        d = a2.x - xv2.x; s0 = fmaf(d, d, s0);  d = b2.x - xv2.x; s1 = fmaf(d, d, s1);
        d = a2.y - xv2.y; s0 = fmaf(d, d, s0);  d = b2.y - xv2.y; s1 = fmaf(d, d, s1);
        d = a2.z - xv2.z; s0 = fmaf(d, d, s0);  d = b2.z - xv2.z; s1 = fmaf(d, d, s1);
        d = a2.w - xv2.w; s0 = fmaf(d, d, s0);  d = b2.w - xv2.w; s1 = fmaf(d, d, s1);
        d = a3.x - xv3.x; s0 = fmaf(d, d, s0);  d = b3.x - xv3.x; s1 = fmaf(d, d, s1);
        d = a3.y - xv3.y; s0 = fmaf(d, d, s0);  d = b3.y - xv3.y; s1 = fmaf(d, d, s1);
        d = a3.z - xv3.z; s0 = fmaf(d, d, s0);  d = b3.z - xv3.z; s1 = fmaf(d, d, s1);
        d = a3.w - xv3.w; s0 = fmaf(d, d, s0);  d = b3.w - xv3.w; s1 = fmaf(d, d, s1);

        // quad reduction (lanes q..q^3 are within the same wave quad)
        s0 += __shfl_xor(s0, 1); s0 += __shfl_xor(s0, 2);
        s1 += __shfl_xor(s1, 1); s1 += __shfl_xor(s1, 2);

        cur = (s1 < s0) ? (c0 + 1) : c0;   // ref: d1 < d0 picks c1 (strict)
    }

    if (q == 0) leaf_out[p] = (float)cur;  // leaf node index 127..254
}

// ---------------- K2: per-leaf sum accumulation ------------------------------
__global__ __launch_bounds__(256) void accumK(const float* __restrict__ img,
                                              const float* __restrict__ leaf_out,
                                              float* __restrict__ S,
                                              unsigned* __restrict__ cnt)
{
    __shared__ float XN[256 * XS];     // staged patches, padded rows   (69632 B)
    __shared__ float Sl[NLEAF * XS];   // per-leaf accumulators         (34816 B)
    __shared__ int   Ll[256];
    __shared__ unsigned cntl[NLEAF];

    const int t = threadIdx.x;
    const int b = blockIdx.x;
    const int p = b * 256 + t;
    const int r = p >> 8, c = p & 255;

    for (int i = t; i < NLEAF * XS; i += 256) Sl[i] = 0.0f;
    if (t < NLEAF) cntl[t] = 0u;

    // stage my patch into row t (stride 68 keeps 16B alignment for b128 writes)
    {
        float* st = &XN[t * XS];
        #pragma unroll
        for (int ki = 0; ki < 8; ++ki) {
            const float4* rowp = (const float4*)(img + (size_t)(r * 8 + ki) * IMG_W + c * 8);
            *(float4*)&st[ki * 8]     = rowp[0];
            *(float4*)&st[ki * 8 + 4] = rowp[1];
        }
    }
    Ll[t] = (int)leaf_out[p] - 127;
    __syncthreads();

    // wave w sweeps its 64 patches; lane k = element k. Per step: all 64 lanes
    // read XN[p][k] (banks 4p+k -> 2 lanes/bank, free) and ds_add to Sl[L][k]
    // (same row, distinct k -> no same-address, no conflicts within the wave).
    const int w = t >> 6, k = t & 63;
    for (int i = 0; i < 64; ++i) {
        const int pl = w * 64 + i;
        const int L  = Ll[pl];                 // wave-uniform broadcast read
        const float x = XN[pl * XS + k];
        atomicAdd(&Sl[L * XS + k], x);
        if (k == 0) atomicAdd(&cntl[L], 1u);
    }
    __syncthreads();

    // flush block sums to global (skip zeros; lane-distinct addresses)
    for (int i = t; i < NLEAF * 64; i += 256) {
        const float v = Sl[(i >> 6) * XS + (i & 63)];
        if (v != 0.0f) atomicAdd(&S[i], v);
    }
    if (t < NLEAF && cntl[t] != 0u) atomicAdd(&cnt[t], cntl[t]);
}

// ---------------- K3: node update (254x64x128 contraction) -------------------
__global__ __launch_bounds__(64) void updateNodes(const float* __restrict__ nodes,
                                                  const float* __restrict__ S,
                                                  const unsigned* __restrict__ cnt,
                                                  float* __restrict__ out)
{
    const int n = blockIdx.x;      // 0..254
    const int k = threadIdx.x;     // 0..63
    if (n == 0) { out[k] = nodes[k]; return; }

    __shared__ float lrL[NLEAF];
    __shared__ float cl[NLEAF];

    const int pos = n + 1;                 // 1-based heap index
    const int Ln = 31 - __clz(pos);        // node level, 1..7
    for (int L = k; L < NLEAF; L += 64) {
        const int a = (128 + L) >> (7 - Ln);
        const int x = pos ^ a;
        const int state = (x == 0) ? Ln : (Ln - (31 - __clz(x)) - 1);
        lrL[L] = 0.3f * ((float)(1 << state) * (1.0f / 128.0f));
        cl[L]  = (float)cnt[L];
    }
    __syncthreads();

    float su = 0.f, sc = 0.f;
    #pragma unroll 8
    for (int L = 0; L < NLEAF; ++L) {
        const float lr = lrL[L];
        su = fmaf(lr, S[L * 64 + k], su);
        sc = fmaf(lr, cl[L], sc);
    }
    const float invP = 1.0f / 65536.0f;
    const float nd = nodes[n * 64 + k];
    out[n * 64 + k] = nd + su * invP - (sc * invP) * nd;
}

extern "C" void kernel_launch(void* const* d_in, const int* in_sizes, int n_in,
                              void* d_out, int out_size, void* d_ws, size_t ws_size,
                              hipStream_t stream)
{
    const float* img   = (const float*)d_in[0];   // 2048*2048 f32
    const float* nodes = (const float*)d_in[1];   // 255*64 f32

    float* out_nodes = (float*)d_out;                 // 255*64
    float* out_leaf  = out_nodes + NUM_NODES * 64;    // 65536 (leaf index as f32)

    float*    S   = (float*)d_ws;                     // 128*64 f32
    unsigned* cnt = (unsigned*)(S + NLEAF * 64);      // 128 u32

    descendK<<<1024, 256, 0, stream>>>(img, nodes, out_leaf, S, cnt);
    accumK<<<256, 256, 0, stream>>>(img, out_leaf, S, cnt);
    updateNodes<<<NUM_NODES, 64, 0, stream>>>(nodes, S, cnt, out_nodes);
}

// Round 4
// 117.656 us; speedup vs baseline: 1.0328x; 1.0328x over previous
//
#include <hip/hip_runtime.h>

#define IMG_W 2048
#define NUM_NODES 255
#define NLEAF 128
#define DEPTH 7
#define RS 68                       // padded LDS row stride (floats)

#define A_FLOATS (256 * RS)         // nodes (255 rows) in phase 1; patch staging XN in phase 2
#define B_FLOATS (NLEAF * RS)       // per-leaf accumulators Sl

// ---------------- K1: fused descend + per-leaf accumulate --------------------
__global__ __launch_bounds__(1024, 4) void fusedK(const float* __restrict__ img,
                                                  const float* __restrict__ nodes,
                                                  float* __restrict__ leaf_out,
                                                  float* __restrict__ S,
                                                  unsigned* __restrict__ cnt)
{
    __shared__ float smem[A_FLOATS + B_FLOATS];   // 104448 B
    __shared__ unsigned cntl[NLEAF];
    __shared__ int Lbuf[256];
    float* nds = smem;                // node table; becomes XN staging after descent
    float* Sl  = smem + A_FLOATS;

    const int t = threadIdx.x;
    const int b = blockIdx.x;

    // zero Sl / cntl (region disjoint from nodes; covered by the first barrier)
    for (int i = t; i < B_FLOATS; i += 1024) Sl[i] = 0.0f;
    if (t < NLEAF) cntl[t] = 0u;

    // cooperative load of the 255x64 node table into padded LDS rows
    const float4* ng = (const float4*)nodes;
    for (int i = t; i < NUM_NODES * 16; i += 1024) {
        *(float4*)&nds[(i >> 4) * RS + (i & 15) * 4] = ng[i];
    }

    // my quarter-patch (issued before the barrier so loads overlap the LDS fill):
    // q = t&3 selects pixel rows 2q, 2q+1 (elements [16q,16q+16))
    const int q = t & 3, g = t >> 2;
    const int p = b * 256 + g;            // patch id
    const int r = p >> 8, c = p & 255;
    float4 xv0, xv1, xv2, xv3;
    {
        const float* row0 = img + (size_t)(r * 8 + 2 * q) * IMG_W + c * 8;
        xv0 = *(const float4*)(row0);
        xv1 = *(const float4*)(row0 + 4);
        const float* row1 = row0 + IMG_W;
        xv2 = *(const float4*)(row1);
        xv3 = *(const float4*)(row1 + 4);
    }
    __syncthreads();

    // descent: 4 lanes/patch, nodes from LDS.
    // bank = (4*row + 16q + 4i + e)%32: shared rows broadcast (free), deep levels ~4-way.
    int cur = 0;
    #pragma unroll
    for (int lvl = 0; lvl < DEPTH; ++lvl) {
        const int c0 = 2 * cur + 1;
        const float* n0 = &nds[c0 * RS + q * 16];
        const float* n1 = n0 + RS;
        const float4 a0 = *(const float4*)(n0);
        const float4 a1 = *(const float4*)(n0 + 4);
        const float4 a2 = *(const float4*)(n0 + 8);
        const float4 a3 = *(const float4*)(n0 + 12);
        const float4 b0 = *(const float4*)(n1);
        const float4 b1 = *(const float4*)(n1 + 4);
        const float4 b2 = *(const float4*)(n1 + 8);
        const float4 b3 = *(const float4*)(n1 + 12);
        float s0 = 0.f, s1 = 0.f, d;
        d = a0.x - xv0.x; s0 = fmaf(d,d,s0);  d = b0.x - xv0.x; s1 = fmaf(d,d,s1);
        d = a0.y - xv0.y; s0 = fmaf(d,d,s0);  d = b0.y - xv0.y; s1 = fmaf(d,d,s1);
        d = a0.z - xv0.z; s0 = fmaf(d,d,s0);  d = b0.z - xv0.z; s1 = fmaf(d,d,s1);
        d = a0.w - xv0.w; s0 = fmaf(d,d,s0);  d = b0.w - xv0.w; s1 = fmaf(d,d,s1);
        d = a1.x - xv1.x; s0 = fmaf(d,d,s0);  d = b1.x - xv1.x; s1 = fmaf(d,d,s1);
        d = a1.y - xv1.y; s0 = fmaf(d,d,s0);  d = b1.y - xv1.y; s1 = fmaf(d,d,s1);
        d = a1.z - xv1.z; s0 = fmaf(d,d,s0);  d = b1.z - xv1.z; s1 = fmaf(d,d,s1);
        d = a1.w - xv1.w; s0 = fmaf(d,d,s0);  d = b1.w - xv1.w; s1 = fmaf(d,d,s1);
        d = a2.x - xv2.x; s0 = fmaf(d,d,s0);  d = b2.x - xv2.x; s1 = fmaf(d,d,s1);
        d = a2.y - xv2.y; s0 = fmaf(d,d,s0);  d = b2.y - xv2.y; s1 = fmaf(d,d,s1);
        d = a2.z - xv2.z; s0 = fmaf(d,d,s0);  d = b2.z - xv2.z; s1 = fmaf(d,d,s1);
        d = a2.w - xv2.w; s0 = fmaf(d,d,s0);  d = b2.w - xv2.w; s1 = fmaf(d,d,s1);
        d = a3.x - xv3.x; s0 = fmaf(d,d,s0);  d = b3.x - xv3.x; s1 = fmaf(d,d,s1);
        d = a3.y - xv3.y; s0 = fmaf(d,d,s0);  d = b3.y - xv3.y; s1 = fmaf(d,d,s1);
        d = a3.z - xv3.z; s0 = fmaf(d,d,s0);  d = b3.z - xv3.z; s1 = fmaf(d,d,s1);
        d = a3.w - xv3.w; s0 = fmaf(d,d,s0);  d = b3.w - xv3.w; s1 = fmaf(d,d,s1);

        // quad reduction (partners t^1, t^2 are in the same quad)
        s0 += __shfl_xor(s0, 1); s0 += __shfl_xor(s0, 2);
        s1 += __shfl_xor(s1, 1); s1 += __shfl_xor(s1, 2);

        cur = (s1 < s0) ? (c0 + 1) : c0;   // ref: d1 < d0 picks c1 (strict)
    }
    __syncthreads();                       // all descents done reading nds

    // stage my quarter into XN row g (overlaying the node table)
    {
        float* st = &nds[g * RS + q * 16];
        *(float4*)(st)      = xv0;
        *(float4*)(st + 4)  = xv1;
        *(float4*)(st + 8)  = xv2;
        *(float4*)(st + 12) = xv3;
    }
    if (q == 0) {
        const int L = cur - 127;
        Lbuf[g] = L;
        leaf_out[p] = (float)cur;          // leaf node index 127..254
        atomicAdd(&cntl[L], 1u);           // once per patch
    }
    __syncthreads();

    // sweep: wave w accumulates its 16 patches; lane k = element k.
    // XN read: bank (4*pl+k)%32 -> 2 lanes/bank (free); Sl atomic: same row,
    // distinct k -> no same-address serialization within the wave.
    const int w = t >> 6, k = t & 63;
    for (int i = 0; i < 16; ++i) {
        const int pl = w * 16 + i;
        const int L  = Lbuf[pl];           // wave-uniform broadcast
        atomicAdd(&Sl[L * RS + k], nds[pl * RS + k]);
    }
    __syncthreads();

    // flush block sums to global S (skip zeros; lane-distinct addresses)
    for (int i = t; i < NLEAF * 64; i += 1024) {
        const float v = Sl[(i >> 6) * RS + (i & 63)];
        if (v != 0.0f) atomicAdd(&S[i], v);
    }
    if (t < NLEAF && cntl[t] != 0u) atomicAdd(&cnt[t], cntl[t]);
}

// ---------------- K2: node update (254x64x128 contraction) -------------------
__global__ __launch_bounds__(256) void updateK(const float* __restrict__ nodes,
                                               const float* __restrict__ S,
                                               const unsigned* __restrict__ cnt,
                                               float* __restrict__ out)
{
    const int gid = blockIdx.x * 256 + threadIdx.x;
    if (gid >= NUM_NODES * 64) return;
    const int n = gid >> 6, k = gid & 63;
    const float nd = nodes[gid];
    if (n == 0) { out[gid] = nd; return; }

    const int pos = n + 1;                 // 1-based heap index
    const int Ln = 31 - __clz(pos);        // node level, 1..7
    float su = 0.f, sc = 0.f;
    #pragma unroll 8
    for (int L = 0; L < NLEAF; ++L) {
        const int a = (128 + L) >> (7 - Ln);   // leaf's ancestor at level Ln
        const int x = pos ^ a;
        const int state = (x == 0) ? Ln : (Ln - (31 - __clz(x)) - 1);
        const float lr = 0.3f * ((float)(1 << state) * (1.0f / 128.0f));
        su = fmaf(lr, S[L * 64 + k], su);
        sc = fmaf(lr, (float)cnt[L], sc);
    }
    const float invP = 1.0f / 65536.0f;
    out[gid] = nd + su * invP - (sc * invP) * nd;
}

extern "C" void kernel_launch(void* const* d_in, const int* in_sizes, int n_in,
                              void* d_out, int out_size, void* d_ws, size_t ws_size,
                              hipStream_t stream)
{
    const float* img   = (const float*)d_in[0];   // 2048*2048 f32
    const float* nodes = (const float*)d_in[1];   // 255*64 f32

    float* out_nodes = (float*)d_out;                 // 255*64
    float* out_leaf  = out_nodes + NUM_NODES * 64;    // 65536 (leaf index as f32)

    float*    S   = (float*)d_ws;                     // 128*64 f32
    unsigned* cnt = (unsigned*)(S + NLEAF * 64);      // 128 u32

    // zero S+cnt via a memset node (cheaper than a kernel dispatch)
    hipMemsetAsync(d_ws, 0, (NLEAF * 64) * sizeof(float) + NLEAF * sizeof(unsigned), stream);

    fusedK<<<256, 1024, 0, stream>>>(img, nodes, out_leaf, S, cnt);
    updateK<<<64, 256, 0, stream>>>(nodes, S, cnt, out_nodes);
}

// Round 5
// 108.759 us; speedup vs baseline: 1.1173x; 1.0818x over previous
//
#include <hip/hip_runtime.h>

#define IMG_W 2048
#define NUM_NODES 255
#define NLEAF 128
#define DEPTH 7
#define RS 68                       // padded LDS row stride (floats); group = (row+q)%8

// DPP xor-butterfly add over 16-lane groups (VALU pipe, not LDS).
// Masks {1,2,7,8} span the 16-group; butterfly partners add the same two values
// (commutative => bit-identical), so all 16 lanes end with the SAME fp sum.
template<int CTRL>
__device__ __forceinline__ float dpp_add(float x) {
    int v = __builtin_amdgcn_update_dpp(0, __float_as_int(x), CTRL, 0xF, 0xF, true);
    return x + __int_as_float(v);
}
__device__ __forceinline__ float group16_sum(float x) {
    x = dpp_add<0xB1>(x);   // quad_perm [1,0,3,2]  : xor 1
    x = dpp_add<0x4E>(x);   // quad_perm [2,3,0,1]  : xor 2
    x = dpp_add<0x141>(x);  // row_half_mirror      : xor 7
    x = dpp_add<0x128>(x);  // row_ror:8            : xor 8
    return x;
}

// ---------------- K1: fused descend + per-leaf accumulate, 16 lanes/patch ----
__global__ __launch_bounds__(1024, 4) void fusedK(const float* __restrict__ img,
                                                  const float* __restrict__ nodes,
                                                  float* __restrict__ leaf_out,
                                                  float* __restrict__ S,
                                                  unsigned* __restrict__ cnt)
{
    __shared__ float nds[NUM_NODES * RS];   // 69360 B
    __shared__ float Sl[NLEAF * RS];        // 34816 B
    __shared__ unsigned cntl[NLEAF];

    const int t = threadIdx.x;
    const int b = blockIdx.x;
    const int g = t >> 4;          // patch-group 0..63
    const int q = t & 15;          // quad within patch (elements 4q..4q+3)
    const int q4 = q * 4;

    // zero per-leaf accumulators
    for (int i = t; i < NLEAF * RS; i += 1024) Sl[i] = 0.0f;
    if (t < NLEAF) cntl[t] = 0u;

    // fill node table (padded rows)
    const float4* ng = (const float4*)nodes;
    for (int i = t; i < NUM_NODES * 16; i += 1024) {
        *(float4*)&nds[(i >> 4) * RS + (i & 15) * 4] = ng[i];
    }

    // prefetch all 4 chunks' patch quads (element e=4q+j -> pixel (q>>1, (q&1)*4+j))
    float4 xv[4];
    #pragma unroll
    for (int ch = 0; ch < 4; ++ch) {
        const int p = b * 256 + ch * 64 + g;
        const int r = p >> 8, c = p & 255;
        xv[ch] = *(const float4*)(img + (size_t)(r * 8 + (q >> 1)) * IMG_W + c * 8 + (q & 1) * 4);
    }
    __syncthreads();

    #pragma unroll
    for (int ch = 0; ch < 4; ++ch) {
        const float4 x = xv[ch];
        int cur = 0;
        #pragma unroll
        for (int lvl = 0; lvl < DEPTH; ++lvl) {
            const int c0 = 2 * cur + 1;
            const float* base = &nds[c0 * RS + q4];
            const float4 a  = *(const float4*)(base);        // child c0, quad q
            const float4 bb = *(const float4*)(base + RS);   // child c0+1, quad q
            float s0 = 0.f, s1 = 0.f, d;
            d = a.x  - x.x; s0 = fmaf(d, d, s0);
            d = a.y  - x.y; s0 = fmaf(d, d, s0);
            d = a.z  - x.z; s0 = fmaf(d, d, s0);
            d = a.w  - x.w; s0 = fmaf(d, d, s0);
            d = bb.x - x.x; s1 = fmaf(d, d, s1);
            d = bb.y - x.y; s1 = fmaf(d, d, s1);
            d = bb.z - x.z; s1 = fmaf(d, d, s1);
            d = bb.w - x.w; s1 = fmaf(d, d, s1);
            s0 = group16_sum(s0);
            s1 = group16_sum(s1);
            cur = (s1 < s0) ? (c0 + 1) : c0;   // ref: d1 < d0 picks c1 (strict)
        }

        const int L = cur - 127;
        if (q == 0) {
            leaf_out[b * 256 + ch * 64 + g] = (float)cur;
            atomicAdd(&cntl[L], 1u);
        }
        // accumulate my quad into the leaf row: addr group (L+q)%8 -> balanced
        float* dst = &Sl[L * RS + q4];
        atomicAdd(dst + 0, x.x);
        atomicAdd(dst + 1, x.y);
        atomicAdd(dst + 2, x.z);
        atomicAdd(dst + 3, x.w);
    }
    __syncthreads();

    // flush block sums to global S (skip zeros; lane-distinct addresses)
    for (int i = t; i < NLEAF * 64; i += 1024) {
        const float v = Sl[(i >> 6) * RS + (i & 63)];
        if (v != 0.0f) atomicAdd(&S[i], v);
    }
    if (t < NLEAF && cntl[t] != 0u) atomicAdd(&cnt[t], cntl[t]);
}

// ---------------- K2: node update (254x64x128 contraction) -------------------
__global__ __launch_bounds__(256) void updateK(const float* __restrict__ nodes,
                                               const float* __restrict__ S,
                                               const unsigned* __restrict__ cnt,
                                               float* __restrict__ out)
{
    const int gid = blockIdx.x * 256 + threadIdx.x;
    if (gid >= NUM_NODES * 64) return;
    const int n = gid >> 6, k = gid & 63;
    const float nd = nodes[gid];
    if (n == 0) { out[gid] = nd; return; }

    const int pos = n + 1;                 // 1-based heap index
    const int Ln = 31 - __clz(pos);        // node level, 1..7
    float su = 0.f, sc = 0.f;
    #pragma unroll 8
    for (int L = 0; L < NLEAF; ++L) {
        const int a = (128 + L) >> (7 - Ln);   // leaf's ancestor at level Ln
        const int x = pos ^ a;
        const int state = (x == 0) ? Ln : (Ln - (31 - __clz(x)) - 1);
        const float lr = 0.3f * ((float)(1 << state) * (1.0f / 128.0f));
        su = fmaf(lr, S[L * 64 + k], su);
        sc = fmaf(lr, (float)cnt[L], sc);
    }
    const float invP = 1.0f / 65536.0f;
    out[gid] = nd + su * invP - (sc * invP) * nd;
}

extern "C" void kernel_launch(void* const* d_in, const int* in_sizes, int n_in,
                              void* d_out, int out_size, void* d_ws, size_t ws_size,
                              hipStream_t stream)
{
    const float* img   = (const float*)d_in[0];   // 2048*2048 f32
    const float* nodes = (const float*)d_in[1];   // 255*64 f32

    float* out_nodes = (float*)d_out;                 // 255*64
    float* out_leaf  = out_nodes + NUM_NODES * 64;    // 65536 (leaf index as f32)

    float*    S   = (float*)d_ws;                     // 128*64 f32
    unsigned* cnt = (unsigned*)(S + NLEAF * 64);      // 128 u32

    hipMemsetAsync(d_ws, 0, (NLEAF * 64) * sizeof(float) + NLEAF * sizeof(unsigned), stream);
    fusedK<<<256, 1024, 0, stream>>>(img, nodes, out_leaf, S, cnt);
    updateK<<<64, 256, 0, stream>>>(nodes, S, cnt, out_nodes);
}